// Round 7
// baseline (463.273 us; speedup 1.0000x reference)
//
#include <hip/hip_runtime.h>

#define B 8
#define C 64
#define N 4096
#define O 64
#define KNN 20
#define PQ 4
#define BN_EPS 1e-5f
#define NEG_SLOPE 0.2f
#define NEG_INF -3.4e38f

typedef _Float16 f16x8 __attribute__((ext_vector_type(8)));
typedef float    f32x4 __attribute__((ext_vector_type(4)));
#define MFMA16(a, b, c) __builtin_amdgcn_mfma_f32_16x16x32_f16(a, b, c, 0, 0, 0)

// insert (r,m) into ascending-sorted top-KNN list with ids, dropping old min.
// precondition: r > d[0]. Tie-safe (insert below existing equal value).
__device__ __forceinline__ void sorted_insert(float (&d)[KNN], int (&id)[KNN],
                                              float r, int m) {
    bool c[KNN];
    #pragma unroll
    for (int j = 0; j < KNN; ++j) c[j] = d[j] < r;
    #pragma unroll
    for (int j = 0; j < KNN - 1; ++j) {
        d[j]  = __builtin_amdgcn_fmed3f(d[j], d[j + 1], r);
        id[j] = c[j + 1] ? id[j + 1] : (c[j] ? m : id[j]);
    }
    d[KNN - 1]  = c[KNN - 1] ? r : d[KNN - 1];
    id[KNN - 1] = c[KNN - 1] ? m : id[KNN - 1];
}

// score-only insert: 19 med3 + 1 max, depth ~2, 20 instrs. Inserting NEG_INF
// is an exact no-op, so callers pass (pass ? sc : NEG_INF) and stay uniform.
__device__ __forceinline__ void insert_score(float (&d)[KNN], float r) {
    #pragma unroll
    for (int j = 0; j < KNN - 1; ++j)
        d[j] = __builtin_amdgcn_fmed3f(d[j], d[j + 1], r);
    d[KNN - 1] = fmaxf(d[KNN - 1], r);
}

// -------- K0: x (B,C,N) -> Xt (B,N,C) fp32, sq = ||x_n||^2, and AHL: f16 hi/lo
// frag-major: per 16-row group (4096 B): [term][khalf][quad][slot16][8 f16]
__global__ __launch_bounds__(256) void k_transpose(const float* __restrict__ x,
                                                   float* __restrict__ Xt,
                                                   float* __restrict__ sq,
                                                   char* __restrict__ AHL) {
    __shared__ float lds[C][65];
    int b    = blockIdx.x >> 6;
    int n0   = (blockIdx.x & 63) << 6;
    int lane = threadIdx.x & 63;
    int w    = threadIdx.x >> 6;
    #pragma unroll
    for (int i = 0; i < 16; ++i) {
        int c = w * 16 + i;
        lds[c][lane] = x[(size_t)b * C * N + (size_t)c * N + n0 + lane];
    }
    __syncthreads();
    #pragma unroll
    for (int i = 0; i < 16; ++i) {
        int nl = w * 16 + i;
        Xt[(size_t)b * N * C + (size_t)(n0 + nl) * C + lane] = lds[lane][nl];
    }
    // sq via quad-partial reduce: thread t owns n=t>>2, c-range (t&3)*16..+16.
    {
        int n_loc = threadIdx.x >> 2;
        int cg    = threadIdx.x & 3;
        float s = 0.f;
        #pragma unroll
        for (int ii = 0; ii < 16; ++ii) {
            float v = lds[cg * 16 + ii][n_loc];
            s = fmaf(v, v, s);
        }
        s += __shfl_xor(s, 1, 64);
        s += __shfl_xor(s, 2, 64);
        if (cg == 0) sq[b * N + n0 + n_loc] = s;
    }
    int s2  = threadIdx.x & 15;
    int rem = threadIdx.x >> 4;
    int qd  = rem & 3;
    int hh  = (rem >> 2) & 1;
    int tt  = rem >> 3;
    int kb  = hh * 32 + qd * 8;
    for (int i = 0; i < 4; ++i) {
        int rowl = i * 16 + s2;
        f16x8 pk;
        #pragma unroll
        for (int ii = 0; ii < 8; ++ii) {
            float v = lds[kb + ii][rowl];
            _Float16 hv = (_Float16)v;
            if (tt) hv = (_Float16)(v - (float)hv);
            pk[ii] = hv;
        }
        char* dst = AHL + ((size_t)b << 20) + (size_t)((n0 >> 4) + i) * 4096
                  + tt * 2048 + hh * 1024 + qd * 256 + s2 * 16;
        *(f16x8*)dst = pk;
    }
}

// -------- K1: a = X*(W1-W2)^T, bvec = X*W2^T
// b = bid&7: XCD-pinned (bid%8 = XCD round-robin) -> Xt[b] (1 MB) L2-local.
__global__ __launch_bounds__(256, 2) void k_ab(const float* __restrict__ Xt,
                                               const float* __restrict__ W,
                                               float* __restrict__ av,
                                               float* __restrict__ bv) {
    int b  = blockIdx.x & 7;
    int n0 = ((blockIdx.x >> 3) & 31) << 7;
    int o  = threadIdx.x & 63;
    int w  = __builtin_amdgcn_readfirstlane((int)(threadIdx.x >> 6));
    float wa[C], wb[C];
    #pragma unroll
    for (int c = 0; c < C; ++c) {
        float w1 = W[o * 2 * C + c];
        float w2 = W[o * 2 * C + C + c];
        wa[c] = w1 - w2;
        wb[c] = w2;
    }
    const float* xb = Xt + (size_t)b * N * C;
    for (int i = 0; i < 32; ++i) {
        int n = n0 + w * 32 + i;
        const float4* xr4 = (const float4*)(xb + (size_t)n * C);
        float aa = 0.f, bb = 0.f;
        #pragma unroll
        for (int c4 = 0; c4 < C / 4; ++c4) {
            float4 xv = xr4[c4];
            aa = fmaf(xv.x, wa[c4 * 4 + 0], aa);
            bb = fmaf(xv.x, wb[c4 * 4 + 0], bb);
            aa = fmaf(xv.y, wa[c4 * 4 + 1], aa);
            bb = fmaf(xv.y, wb[c4 * 4 + 1], bb);
            aa = fmaf(xv.z, wa[c4 * 4 + 2], aa);
            bb = fmaf(xv.z, wb[c4 * 4 + 2], bb);
            aa = fmaf(xv.w, wa[c4 * 4 + 3], aa);
            bb = fmaf(xv.w, wb[c4 * 4 + 3], bb);
        }
        size_t oidx = ((size_t)b * N + n) * O + o;
        av[oidx] = aa;
        bv[oidx] = bb;
    }
}

// -------- K2: two-phase streaming MFMA kNN. Zero LDS, zero __syncthreads.
// 1-wave blocks, grid 4096, b = bid&7 (XCD-pinned), h = bit3, qg = bid>>4.
// R6 post-mortem: kernel is VALU-ISSUE-bound (4 scheduling configs all
// 248-253 us); the 77-instr score+id insert via the drain path was ~60% of
// the stream. This version splits selection:
//  PHASE 1: per-lane top-20 SCORES only (insert = 19 med3 + 1 max = 20
//   instrs; NEG_INF insert is a no-op so the triggered block is uniform,
//   no queue, no divergent body). Quad tournament -> T = exact 20th score
//   of the query-half.
//  PHASE 2: rescan (A-frags re-stream from L2, MFMA recomputed bitwise-
//   identically), filter sc >= T (&& sc > d2[0]) - pass rate ~1%, run the
//   old queue + full insert only on that trickle. Same scan order + same
//   insert-below-equal => identical selection & tie semantics as R6.
// Tripwire: WRITE_SIZE must stay ~10240 KB (spill detector).
__global__ __launch_bounds__(64, 2) void k_knn(const char* __restrict__ AHL,
                                               const float* __restrict__ sq,
                                               float* __restrict__ pdg,
                                               int* __restrict__ pig) {
    int bid  = blockIdx.x;
    int qg   = bid >> 4;
    int b    = bid & 7;
    int h    = (bid >> 3) & 1;
    int lane = threadIdx.x & 63;
    int quad = lane >> 4;
    const char*  AHLb = AHL + ((size_t)b << 20);
    const float* sqb  = sq + b * N;
    int cbase0 = h * (N / 2);
    const char* Asrc = AHLb + (size_t)cbase0 * 256;

    // B-frags: this wave's query group qg: hi/lo x khalf (16 VGPRs)
    const char* qb = AHLb + (size_t)qg * 4096 + lane * 16;
    f16x8 bh0 = *(const f16x8*)(qb);
    f16x8 bh1 = *(const f16x8*)(qb + 1024);
    f16x8 bl0 = *(const f16x8*)(qb + 2048);
    f16x8 bl1 = *(const f16x8*)(qb + 3072);

    // ================= PHASE 1: scores only =================
    float d[KNN];

    // prefetch iter 0
    const char* p0 = Asrc + lane * 16;
    f16x8 na0 = *(const f16x8*)(p0);
    f16x8 na1 = *(const f16x8*)(p0 + 1024);
    f16x8 na2 = *(const f16x8*)(p0 + 2048);
    f16x8 na3 = *(const f16x8*)(p0 + 3072);
    float4 nsq = *(const float4*)(sqb + cbase0 + quad * 4);

    // warm-fill: iters 0..4 (20 cands per lane) fill all KNN score slots
    #pragma unroll
    for (int it = 0; it < 5; ++it) {
        f16x8 a0 = na0, a1 = na1, a2 = na2, a3 = na3;
        float4 sqv = nsq;
        {
            const char* p = Asrc + (size_t)(it + 1) * 4096 + lane * 16;
            na0 = *(const f16x8*)(p);
            na1 = *(const f16x8*)(p + 1024);
            na2 = *(const f16x8*)(p + 2048);
            na3 = *(const f16x8*)(p + 3072);
            nsq = *(const float4*)(sqb + cbase0 + (it + 1) * 16 + quad * 4);
        }
        f32x4 acc = {0.f, 0.f, 0.f, 0.f};
        acc = MFMA16(a0, bh0, acc);
        acc = MFMA16(a1, bh1, acc);
        acc = MFMA16(a0, bl0, acc);
        acc = MFMA16(a1, bl1, acc);
        acc = MFMA16(a2, bh0, acc);
        acc = MFMA16(a3, bh1, acc);
        #pragma unroll
        for (int r = 0; r < 4; ++r) {
            float sc = fmaf(2.f, acc[r],
                            -((r == 0) ? sqv.x : (r == 1) ? sqv.y
                                       : (r == 2) ? sqv.z : sqv.w));
            d[it * 4 + r] = sc;           // compile-time slot index
        }
    }
    // one-time in-register bubble sort, ascending (scores only)
    #pragma unroll
    for (int i = 0; i < KNN - 1; ++i) {
        #pragma unroll
        for (int j = 0; j < KNN - 1 - i; ++j) {
            float lo = fminf(d[j], d[j + 1]);
            float hi = fmaxf(d[j], d[j + 1]);
            d[j] = lo; d[j + 1] = hi;
        }
    }
    // shared threshold across the 4 quad-lanes serving this query
    float thr = d[0];
    thr = fmaxf(thr, __shfl_xor(thr, 16, 64));
    thr = fmaxf(thr, __shfl_xor(thr, 32, 64));

    #pragma unroll 1
    for (int it = 5; it < 128; ++it) {         // 16 cands per iter
        f16x8 a0 = na0, a1 = na1, a2 = na2, a3 = na3;
        float4 sqv = nsq;
        if (it + 1 < 128) {                    // issue next-iter loads early
            const char* p = Asrc + (size_t)(it + 1) * 4096 + lane * 16;
            na0 = *(const f16x8*)(p);
            na1 = *(const f16x8*)(p + 1024);
            na2 = *(const f16x8*)(p + 2048);
            na3 = *(const f16x8*)(p + 3072);
            nsq = *(const float4*)(sqb + cbase0 + (it + 1) * 16 + quad * 4);
        }
        f32x4 acc = {0.f, 0.f, 0.f, 0.f};
        acc = MFMA16(a0, bh0, acc);
        acc = MFMA16(a1, bh1, acc);
        acc = MFMA16(a0, bl0, acc);
        acc = MFMA16(a1, bl1, acc);
        acc = MFMA16(a2, bh0, acc);
        acc = MFMA16(a3, bh1, acc);
        #pragma unroll
        for (int r = 0; r < 4; ++r) {
            float sc = fmaf(2.f, acc[r],
                            -((r == 0) ? sqv.x : (r == 1) ? sqv.y
                                       : (r == 2) ? sqv.z : sqv.w));
            bool pass = sc > thr;
            if (__any(pass)) {
                insert_score(d, pass ? sc : NEG_INF);  // uniform, no branch
                float t = d[0];                        // refresh threshold
                t = fmaxf(t, __shfl_xor(t, 16, 64));
                t = fmaxf(t, __shfl_xor(t, 32, 64));
                thr = t;                               // monotone >= old thr
            }
        }
    }
    // score-only quad tournament: 2,3 -> 0,1 then 1 -> 0
    #pragma unroll 1
    for (int step = 0; step < 2; ++step) {
        int off = (step == 0) ? 32 : 16;
        bool active = (step == 0) ? (quad < 2) : (quad == 0);
        for (int j = KNN - 1; j >= 0; --j) {   // descending; early-exit
            float rv = __shfl(d[j], lane + off, 64);
            bool ins = active && (rv > d[0]);
            if (!__any(ins)) break;
            insert_score(d, ins ? rv : NEG_INF);
        }
    }
    // exact 20th-largest score of this query-half, broadcast to all 4 lanes
    float T = __shfl(d[0], lane & 15, 64);

    // ================= PHASE 2: index recovery =================
    float d2[KNN]; int id2[KNN];
    #pragma unroll
    for (int j = 0; j < KNN; ++j) { d2[j] = NEG_INF; id2[j] = 0; }
    float pv[PQ]; int pi[PQ]; int pc = 0;
    #pragma unroll
    for (int j = 0; j < PQ; ++j) { pv[j] = 0.f; pi[j] = 0; }

    // re-prefetch iter 0 (A-frags now L2-resident)
    na0 = *(const f16x8*)(p0);
    na1 = *(const f16x8*)(p0 + 1024);
    na2 = *(const f16x8*)(p0 + 2048);
    na3 = *(const f16x8*)(p0 + 3072);
    nsq = *(const float4*)(sqb + cbase0 + quad * 4);

    #pragma unroll 1
    for (int it = 0; it < 128; ++it) {
        f16x8 a0 = na0, a1 = na1, a2 = na2, a3 = na3;
        float4 sqv = nsq;
        if (it + 1 < 128) {
            const char* p = Asrc + (size_t)(it + 1) * 4096 + lane * 16;
            na0 = *(const f16x8*)(p);
            na1 = *(const f16x8*)(p + 1024);
            na2 = *(const f16x8*)(p + 2048);
            na3 = *(const f16x8*)(p + 3072);
            nsq = *(const float4*)(sqb + cbase0 + (it + 1) * 16 + quad * 4);
        }
        f32x4 acc = {0.f, 0.f, 0.f, 0.f};
        acc = MFMA16(a0, bh0, acc);
        acc = MFMA16(a1, bh1, acc);
        acc = MFMA16(a0, bl0, acc);
        acc = MFMA16(a1, bl1, acc);
        acc = MFMA16(a2, bh0, acc);
        acc = MFMA16(a3, bh1, acc);
        int c0 = cbase0 + it * 16 + quad * 4;  // lane's 4 cands (row=quad*4+r)
        #pragma unroll
        for (int r = 0; r < 4; ++r) {
            float sc = fmaf(2.f, acc[r],       // bitwise == phase-1 score
                            -((r == 0) ? sqv.x : (r == 1) ? sqv.y
                                       : (r == 2) ? sqv.z : sqv.w));
            if (sc >= T && sc > d2[0]) {       // ~1% pass rate
                #pragma unroll
                for (int j = 0; j < PQ; ++j) {
                    bool sel = (pc == j);
                    pv[j] = sel ? sc : pv[j];
                    pi[j] = sel ? (c0 + r) : pi[j];
                }
                ++pc;
            }
            if (__any(pc == PQ)) {             // drain all lanes in parallel
                #pragma unroll
                for (int j = 0; j < PQ; ++j)
                    if (j < pc && pv[j] > d2[0]) sorted_insert(d2, id2, pv[j], pi[j]);
                pc = 0;
            }
        }
    }
    #pragma unroll
    for (int j = 0; j < PQ; ++j)               // final flush
        if (j < pc && pv[j] > d2[0]) sorted_insert(d2, id2, pv[j], pi[j]);

    // in-wave quad-merge tournament with ids: 2,3 -> 0,1 then 1 -> 0
    #pragma unroll 1
    for (int step = 0; step < 2; ++step) {
        int off = (step == 0) ? 32 : 16;
        bool active = (step == 0) ? (quad < 2) : (quad == 0);
        for (int j = KNN - 1; j >= 0; --j) {   // descending; early-exit
            float rv = __shfl(d2[j], lane + off, 64);
            int   ri = __shfl(id2[j], lane + off, 64);
            bool ins = active && (rv > d2[0]);
            if (!__any(ins)) break;
            if (ins) sorted_insert(d2, id2, rv, ri);
        }
    }
    if (lane < 16) {
        size_t rr = (size_t)b * N + qg * 16 + lane;
        float* po = pdg + (rr * 2 + h) * KNN;
        int*   qo = pig + (rr * 2 + h) * KNN;
        #pragma unroll
        for (int j = 0; j < KNN; ++j) { po[j] = d2[j]; qo[j] = id2[j]; }
    }
}

// -------- K2b: merge the 2 sorted half-lists per query -> knn indices
__global__ __launch_bounds__(128) void k_merge(const float* __restrict__ pdg,
                                               const int* __restrict__ pig,
                                               int* __restrict__ knn) {
    __shared__ float sd[128][41];
    __shared__ int   si[128][41];
    int t = threadIdx.x;
    size_t rr = (size_t)blockIdx.x * 128 + t;
    const float* pr = pdg + rr * (2 * KNN);
    const int*   qr = pig + rr * (2 * KNN);
    #pragma unroll
    for (int j = 0; j < 2 * KNN; ++j) { sd[t][j] = pr[j]; si[t][j] = qr[j]; }
    int i = KNN - 1, j = KNN - 1;
    int* op = knn + rr * KNN;
    for (int o = 0; o < KNN; ++o) {
        bool t0 = (j < 0) || (i >= 0 && sd[t][i] >= sd[t][KNN + j]);
        op[o] = t0 ? si[t][i] : si[t][KNN + j];
        if (t0) --i; else --j;
    }
}

// -------- K3: out[b][o][n] = leaky(scale*(a[n][o] + max_k bvec[idx_k][o]) + bias)
// b = bid&7: XCD-pinned -> each XCD gathers only its own bv[b] (1 MB, L2-res).
__global__ __launch_bounds__(256) void k_out(const float* __restrict__ av,
                                             const float* __restrict__ bv,
                                             const int* __restrict__ knn,
                                             const float* __restrict__ gamma,
                                             const float* __restrict__ beta,
                                             const float* __restrict__ rmean,
                                             const float* __restrict__ rvar,
                                             float* __restrict__ out) {
    __shared__ float lds[64][65];
    int b    = blockIdx.x & 7;
    int n0   = (blockIdx.x >> 3) << 6;
    int lane = threadIdx.x & 63;
    int w    = __builtin_amdgcn_readfirstlane((int)(threadIdx.x >> 6));
    int o    = lane;
    float scale = gamma[o] * rsqrtf(rvar[o] + BN_EPS);
    float bias  = fmaf(-rmean[o], scale, beta[o]);
    const float* bvb = bv + (size_t)b * N * O;
    for (int i = 0; i < 16; ++i) {
        int n = n0 + w * 16 + i;
        const int* kn = knn + ((size_t)b * N + n) * KNN;
        float mx = -3.4e38f, mn = 3.4e38f;
        #pragma unroll
        for (int j = 0; j < KNN; ++j) {
            float v = bvb[(size_t)kn[j] * O + o];
            mx = fmaxf(mx, v);
            mn = fminf(mn, v);
        }
        float a   = av[((size_t)b * N + n) * O + o];
        float sel = (scale >= 0.f) ? (a + mx) : (a + mn);
        float y   = fmaf(sel, scale, bias);
        y = fmaxf(y, NEG_SLOPE * y);
        lds[o][w * 16 + i] = y;
    }
    __syncthreads();
    int r  = threadIdx.x >> 2;
    int c0 = (threadIdx.x & 3) << 4;
    float* ob = out + (size_t)b * O * N + (size_t)r * N + n0;
    #pragma unroll
    for (int j = 0; j < 16; j += 4) {
        float4 v;
        v.x = lds[r][c0 + j + 0];
        v.y = lds[r][c0 + j + 1];
        v.z = lds[r][c0 + j + 2];
        v.w = lds[r][c0 + j + 3];
        *(float4*)(ob + c0 + j) = v;
    }
}

extern "C" void kernel_launch(void* const* d_in, const int* in_sizes, int n_in,
                              void* d_out, int out_size, void* d_ws, size_t ws_size,
                              hipStream_t stream) {
    const float* x     = (const float*)d_in[0];
    const float* W     = (const float*)d_in[1];
    const float* gamma = (const float*)d_in[2];
    const float* beta  = (const float*)d_in[3];
    const float* rmean = (const float*)d_in[4];
    const float* rvar  = (const float*)d_in[5];
    float* out = (float*)d_out;

    char* wsb = (char*)d_ws;
    float* Xt  = (float*)(wsb);                 //  8 MB
    float* sqn = (float*)(wsb + 8388608);       //  128 KB
    float* av  = (float*)(wsb + 8519680);       //  8 MB
    float* bvv = (float*)(wsb + 16908288);      //  8 MB
    int*   knn = (int*)  (wsb + 25296896);      //  2.5 MB
    char*  AHL =         (wsb + 27918336);      //  8 MB f16 hi/lo frag-major
    float* pdg = (float*)(wsb + 36306944);      //  5.24 MB partial dists
    int*   pig = (int*)  (wsb + 41549824);      //  5.24 MB partial ids

    k_transpose<<<512, 256, 0, stream>>>(x, Xt, sqn, AHL);
    k_ab<<<256, 256, 0, stream>>>(Xt, W, av, bvv);
    k_knn<<<4096, 64, 0, stream>>>(AHL, sqn, pdg, pig);
    k_merge<<<256, 128, 0, stream>>>(pdg, pig, knn);
    k_out<<<512, 256, 0, stream>>>(av, bvv, knn, gamma, beta, rmean, rvar, out);
}

// Round 8
// 426.369 us; speedup vs baseline: 1.0866x; 1.0866x over previous
//
#include <hip/hip_runtime.h>

#define B 8
#define C 64
#define N 4096
#define O 64
#define KNN 20
#define PQ 2
#define BN_EPS 1e-5f
#define NEG_SLOPE 0.2f

typedef _Float16 f16x8 __attribute__((ext_vector_type(8)));
typedef float    f32x4 __attribute__((ext_vector_type(4)));
#define MFMA16(a, b, c) __builtin_amdgcn_mfma_f32_16x16x32_f16(a, b, c, 0, 0, 0)

// insert (r,m) into ascending-sorted top-KNN list, dropping old min d[0].
// precondition: r > d[0]. Tie-safe (insert below existing equal value).
// Branch-free parallel form: new_d[j] = med3(d[j], d[j+1], r); depth ~2.
__device__ __forceinline__ void sorted_insert(float (&d)[KNN], int (&id)[KNN],
                                              float r, int m) {
    bool c[KNN];
    #pragma unroll
    for (int j = 0; j < KNN; ++j) c[j] = d[j] < r;
    #pragma unroll
    for (int j = 0; j < KNN - 1; ++j) {
        d[j]  = __builtin_amdgcn_fmed3f(d[j], d[j + 1], r);
        id[j] = c[j + 1] ? id[j + 1] : (c[j] ? m : id[j]);
    }
    d[KNN - 1]  = c[KNN - 1] ? r : d[KNN - 1];
    id[KNN - 1] = c[KNN - 1] ? m : id[KNN - 1];
}

// -------- K0: x (B,C,N) -> Xt (B,N,C) fp32, sq = ||x_n||^2, and AHL: f16 hi/lo
// frag-major: per 16-row group (4096 B): [term][khalf][quad][slot16][8 f16]
__global__ __launch_bounds__(256) void k_transpose(const float* __restrict__ x,
                                                   float* __restrict__ Xt,
                                                   float* __restrict__ sq,
                                                   char* __restrict__ AHL) {
    __shared__ float lds[C][65];
    int b    = blockIdx.x >> 6;
    int n0   = (blockIdx.x & 63) << 6;
    int lane = threadIdx.x & 63;
    int w    = threadIdx.x >> 6;
    #pragma unroll
    for (int i = 0; i < 16; ++i) {
        int c = w * 16 + i;
        lds[c][lane] = x[(size_t)b * C * N + (size_t)c * N + n0 + lane];
    }
    __syncthreads();
    #pragma unroll
    for (int i = 0; i < 16; ++i) {
        int nl = w * 16 + i;
        Xt[(size_t)b * N * C + (size_t)(n0 + nl) * C + lane] = lds[lane][nl];
    }
    // sq via quad-partial reduce: thread t owns n=t>>2, c-range (t&3)*16..+16.
    {
        int n_loc = threadIdx.x >> 2;
        int cg    = threadIdx.x & 3;
        float s = 0.f;
        #pragma unroll
        for (int ii = 0; ii < 16; ++ii) {
            float v = lds[cg * 16 + ii][n_loc];
            s = fmaf(v, v, s);
        }
        s += __shfl_xor(s, 1, 64);
        s += __shfl_xor(s, 2, 64);
        if (cg == 0) sq[b * N + n0 + n_loc] = s;
    }
    int s2  = threadIdx.x & 15;
    int rem = threadIdx.x >> 4;
    int qd  = rem & 3;
    int hh  = (rem >> 2) & 1;
    int tt  = rem >> 3;
    int kb  = hh * 32 + qd * 8;
    for (int i = 0; i < 4; ++i) {
        int rowl = i * 16 + s2;
        f16x8 pk;
        #pragma unroll
        for (int ii = 0; ii < 8; ++ii) {
            float v = lds[kb + ii][rowl];
            _Float16 hv = (_Float16)v;
            if (tt) hv = (_Float16)(v - (float)hv);
            pk[ii] = hv;
        }
        char* dst = AHL + ((size_t)b << 20) + (size_t)((n0 >> 4) + i) * 4096
                  + tt * 2048 + hh * 1024 + qd * 256 + s2 * 16;
        *(f16x8*)dst = pk;
    }
}

// -------- K1: a = X*(W1-W2)^T, bvec = X*W2^T
// b = bid&7: XCD-pinned (bid%8 = XCD round-robin) -> Xt[b] (1 MB) L2-local.
__global__ __launch_bounds__(256, 2) void k_ab(const float* __restrict__ Xt,
                                               const float* __restrict__ W,
                                               float* __restrict__ av,
                                               float* __restrict__ bv) {
    int b  = blockIdx.x & 7;
    int n0 = ((blockIdx.x >> 3) & 31) << 7;
    int o  = threadIdx.x & 63;
    int w  = __builtin_amdgcn_readfirstlane((int)(threadIdx.x >> 6));
    float wa[C], wb[C];
    #pragma unroll
    for (int c = 0; c < C; ++c) {
        float w1 = W[o * 2 * C + c];
        float w2 = W[o * 2 * C + C + c];
        wa[c] = w1 - w2;
        wb[c] = w2;
    }
    const float* xb = Xt + (size_t)b * N * C;
    for (int i = 0; i < 32; ++i) {
        int n = n0 + w * 32 + i;
        const float4* xr4 = (const float4*)(xb + (size_t)n * C);
        float aa = 0.f, bb = 0.f;
        #pragma unroll
        for (int c4 = 0; c4 < C / 4; ++c4) {
            float4 xv = xr4[c4];
            aa = fmaf(xv.x, wa[c4 * 4 + 0], aa);
            bb = fmaf(xv.x, wb[c4 * 4 + 0], bb);
            aa = fmaf(xv.y, wa[c4 * 4 + 1], aa);
            bb = fmaf(xv.y, wb[c4 * 4 + 1], bb);
            aa = fmaf(xv.z, wa[c4 * 4 + 2], aa);
            bb = fmaf(xv.z, wb[c4 * 4 + 2], bb);
            aa = fmaf(xv.w, wa[c4 * 4 + 3], aa);
            bb = fmaf(xv.w, wb[c4 * 4 + 3], bb);
        }
        size_t oidx = ((size_t)b * N + n) * O + o;
        av[oidx] = aa;
        bv[oidx] = bb;
    }
}

// -------- K2: single-pass streaming MFMA kNN (R6 structure: proven 252 us).
// 1-wave blocks, grid 4096, b = bid&7 (XCD-pinned), h = bit3, qg = bid>>4.
// R7 post-mortem: two-phase rescan + per-step shfl chain regressed (368 us);
// wave-ANY over 16 queries fires ~every candidate, so only per-event cost
// matters, and no shfl belongs in the per-step path. PQ=2 (vs 4): drain
// cost x rate is PQ-invariant, but append block halves (2 select-pairs).
// Tripwire: WRITE_SIZE ~10240 KB (spill detector); launch_bounds(64,2)
// keeps the VGPR cap high (R2: (64,4) clamp -> scratch catastrophe).
__global__ __launch_bounds__(64, 2) void k_knn(const char* __restrict__ AHL,
                                               const float* __restrict__ sq,
                                               float* __restrict__ pdg,
                                               int* __restrict__ pig) {
    int bid  = blockIdx.x;
    int qg   = bid >> 4;
    int b    = bid & 7;
    int h    = (bid >> 3) & 1;
    int lane = threadIdx.x & 63;
    int quad = lane >> 4;
    const char*  AHLb = AHL + ((size_t)b << 20);
    const float* sqb  = sq + b * N;
    int cbase0 = h * (N / 2);
    const char* Asrc = AHLb + (size_t)cbase0 * 256;

    // B-frags: this wave's query group qg: hi/lo x khalf (16 VGPRs)
    const char* qb = AHLb + (size_t)qg * 4096 + lane * 16;
    f16x8 bh0 = *(const f16x8*)(qb);
    f16x8 bh1 = *(const f16x8*)(qb + 1024);
    f16x8 bl0 = *(const f16x8*)(qb + 2048);
    f16x8 bl1 = *(const f16x8*)(qb + 3072);

    float d[KNN]; int id[KNN];
    float pv[PQ]; int pi[PQ]; int pc = 0;
    #pragma unroll
    for (int j = 0; j < PQ; ++j) { pv[j] = 0.f; pi[j] = 0; }

    // prefetch iter 0
    const char* p0 = Asrc + lane * 16;
    f16x8 na0 = *(const f16x8*)(p0);
    f16x8 na1 = *(const f16x8*)(p0 + 1024);
    f16x8 na2 = *(const f16x8*)(p0 + 2048);
    f16x8 na3 = *(const f16x8*)(p0 + 3072);
    float4 nsq = *(const float4*)(sqb + cbase0 + quad * 4);

    // ---- warm-fill: iters 0..4 (20 cands per lane) fill all KNN slots
    #pragma unroll
    for (int it = 0; it < 5; ++it) {
        f16x8 a0 = na0, a1 = na1, a2 = na2, a3 = na3;
        float4 sqv = nsq;
        {
            const char* p = Asrc + (size_t)(it + 1) * 4096 + lane * 16;
            na0 = *(const f16x8*)(p);
            na1 = *(const f16x8*)(p + 1024);
            na2 = *(const f16x8*)(p + 2048);
            na3 = *(const f16x8*)(p + 3072);
            nsq = *(const float4*)(sqb + cbase0 + (it + 1) * 16 + quad * 4);
        }
        f32x4 acc = {0.f, 0.f, 0.f, 0.f};
        acc = MFMA16(a0, bh0, acc);
        acc = MFMA16(a1, bh1, acc);
        acc = MFMA16(a0, bl0, acc);
        acc = MFMA16(a1, bl1, acc);
        acc = MFMA16(a2, bh0, acc);
        acc = MFMA16(a3, bh1, acc);
        int c0 = cbase0 + it * 16 + quad * 4;
        #pragma unroll
        for (int r = 0; r < 4; ++r) {
            float sc = fmaf(2.f, acc[r],
                            -((r == 0) ? sqv.x : (r == 1) ? sqv.y
                                       : (r == 2) ? sqv.z : sqv.w));
            d[it * 4 + r]  = sc;          // compile-time slot index
            id[it * 4 + r] = c0 + r;
        }
    }
    // one-time in-register bubble sort, ascending (compile-time indices)
    #pragma unroll
    for (int i = 0; i < KNN - 1; ++i) {
        #pragma unroll
        for (int j = 0; j < KNN - 1 - i; ++j) {
            bool sw = d[j] > d[j + 1];
            float tv = d[j]; int ti = id[j];
            d[j]      = sw ? d[j + 1] : d[j];
            id[j]     = sw ? id[j + 1] : id[j];
            d[j + 1]  = sw ? tv : d[j + 1];
            id[j + 1] = sw ? ti : id[j + 1];
        }
    }
    // shared threshold across the 4 quad-lanes serving this query
    float thr = d[0];
    thr = fmaxf(thr, __shfl_xor(thr, 16, 64));
    thr = fmaxf(thr, __shfl_xor(thr, 32, 64));

    #pragma unroll 1
    for (int it = 5; it < 128; ++it) {         // 16 cands per iter
        f16x8 a0 = na0, a1 = na1, a2 = na2, a3 = na3;
        float4 sqv = nsq;
        if (it + 1 < 128) {                    // issue next-iter loads early
            const char* p = Asrc + (size_t)(it + 1) * 4096 + lane * 16;
            na0 = *(const f16x8*)(p);
            na1 = *(const f16x8*)(p + 1024);
            na2 = *(const f16x8*)(p + 2048);
            na3 = *(const f16x8*)(p + 3072);
            nsq = *(const float4*)(sqb + cbase0 + (it + 1) * 16 + quad * 4);
        }
        f32x4 acc = {0.f, 0.f, 0.f, 0.f};
        acc = MFMA16(a0, bh0, acc);
        acc = MFMA16(a1, bh1, acc);
        acc = MFMA16(a0, bl0, acc);
        acc = MFMA16(a1, bl1, acc);
        acc = MFMA16(a2, bh0, acc);
        acc = MFMA16(a3, bh1, acc);
        int c0 = cbase0 + it * 16 + quad * 4;  // lane's 4 cands (row=quad*4+r)
        #pragma unroll
        for (int r = 0; r < 4; ++r) {
            float sc = fmaf(2.f, acc[r],
                            -((r == 0) ? sqv.x : (r == 1) ? sqv.y
                                       : (r == 2) ? sqv.z : sqv.w));
            if (sc > thr) {                    // global-ish filter
                #pragma unroll
                for (int j = 0; j < PQ; ++j) {
                    bool sel = (pc == j);
                    pv[j] = sel ? sc : pv[j];
                    pi[j] = sel ? (c0 + r) : pi[j];
                }
                ++pc;
            }
            if (__any(pc == PQ)) {             // drain all lanes in parallel
                #pragma unroll
                for (int j = 0; j < PQ; ++j)
                    if (j < pc && pv[j] > d[0]) sorted_insert(d, id, pv[j], pi[j]);
                pc = 0;
                float t = d[0];                // refresh shared threshold
                t = fmaxf(t, __shfl_xor(t, 16, 64));
                t = fmaxf(t, __shfl_xor(t, 32, 64));
                thr = fmaxf(thr, t);
            }
        }
    }
    #pragma unroll
    for (int j = 0; j < PQ; ++j)               // final flush
        if (j < pc && pv[j] > d[0]) sorted_insert(d, id, pv[j], pi[j]);

    // in-wave quad-merge tournament via shuffles: 2,3 -> 0,1 then 1 -> 0
    #pragma unroll 1
    for (int step = 0; step < 2; ++step) {
        int off = (step == 0) ? 32 : 16;
        bool active = (step == 0) ? (quad < 2) : (quad == 0);
        for (int j = KNN - 1; j >= 0; --j) {   // descending; early-exit
            float rv = __shfl(d[j], lane + off, 64);
            int   ri = __shfl(id[j], lane + off, 64);
            bool ins = active && (rv > d[0]);
            if (!__any(ins)) break;
            if (ins) sorted_insert(d, id, rv, ri);
        }
    }
    if (lane < 16) {
        size_t rr = (size_t)b * N + qg * 16 + lane;
        float* po = pdg + (rr * 2 + h) * KNN;
        int*   qo = pig + (rr * 2 + h) * KNN;
        #pragma unroll
        for (int j = 0; j < KNN; ++j) { po[j] = d[j]; qo[j] = id[j]; }
    }
}

// -------- K3: fused merge + gather + BN/leaky + transpose-store.
// Phase A: threads 0..63 merge the 2 sorted half-lists of their n (reading
// pdg/pig straight from L2) into LDS ids[64][21]. Phase B: gather.
// b = bid&7: XCD-pinned -> each XCD gathers only its own bv[b] (1 MB, L2-res).
__global__ __launch_bounds__(256) void k_out(const float* __restrict__ av,
                                             const float* __restrict__ bv,
                                             const float* __restrict__ pdg,
                                             const int* __restrict__ pig,
                                             const float* __restrict__ gamma,
                                             const float* __restrict__ beta,
                                             const float* __restrict__ rmean,
                                             const float* __restrict__ rvar,
                                             float* __restrict__ out) {
    __shared__ float lds[64][65];
    __shared__ int   ids[64][21];
    int b    = blockIdx.x & 7;
    int n0   = (blockIdx.x >> 3) << 6;
    int t    = threadIdx.x;
    int lane = t & 63;
    int w    = __builtin_amdgcn_readfirstlane((int)(t >> 6));
    // ---- phase A: per-query 2-way merge of sorted half-lists (top KNN)
    if (t < 64) {
        size_t rr = (size_t)b * N + n0 + t;
        const float* pr = pdg + rr * (2 * KNN);
        const int*   qr = pig + rr * (2 * KNN);
        int i = KNN - 1, j = KNN - 1;
        #pragma unroll 1
        for (int o = 0; o < KNN; ++o) {
            bool t0 = (j < 0) || (i >= 0 && pr[i] >= pr[KNN + j]);
            ids[t][o] = t0 ? qr[i] : qr[KNN + j];
            if (t0) --i; else --j;
        }
    }
    __syncthreads();
    // ---- phase B: gather + epilogue
    int o = lane;
    float scale = gamma[o] * rsqrtf(rvar[o] + BN_EPS);
    float bias  = fmaf(-rmean[o], scale, beta[o]);
    const float* bvb = bv + (size_t)b * N * O;
    for (int i = 0; i < 16; ++i) {
        int nl = w * 16 + i;
        int n  = n0 + nl;
        float mx = -3.4e38f, mn = 3.4e38f;
        #pragma unroll
        for (int j = 0; j < KNN; ++j) {
            float v = bvb[(size_t)ids[nl][j] * O + o];
            mx = fmaxf(mx, v);
            mn = fminf(mn, v);
        }
        float a   = av[((size_t)b * N + n) * O + o];
        float sel = (scale >= 0.f) ? (a + mx) : (a + mn);
        float y   = fmaf(sel, scale, bias);
        y = fmaxf(y, NEG_SLOPE * y);
        lds[o][nl] = y;
    }
    __syncthreads();
    int r  = threadIdx.x >> 2;
    int c0 = (threadIdx.x & 3) << 4;
    float* ob = out + (size_t)b * O * N + (size_t)r * N + n0;
    #pragma unroll
    for (int j = 0; j < 16; j += 4) {
        float4 v;
        v.x = lds[r][c0 + j + 0];
        v.y = lds[r][c0 + j + 1];
        v.z = lds[r][c0 + j + 2];
        v.w = lds[r][c0 + j + 3];
        *(float4*)(ob + c0 + j) = v;
    }
}

extern "C" void kernel_launch(void* const* d_in, const int* in_sizes, int n_in,
                              void* d_out, int out_size, void* d_ws, size_t ws_size,
                              hipStream_t stream) {
    const float* x     = (const float*)d_in[0];
    const float* W     = (const float*)d_in[1];
    const float* gamma = (const float*)d_in[2];
    const float* beta  = (const float*)d_in[3];
    const float* rmean = (const float*)d_in[4];
    const float* rvar  = (const float*)d_in[5];
    float* out = (float*)d_out;

    char* wsb = (char*)d_ws;
    float* Xt  = (float*)(wsb);                 //  8 MB
    float* sqn = (float*)(wsb + 8388608);       //  128 KB
    float* av  = (float*)(wsb + 8519680);       //  8 MB
    float* bvv = (float*)(wsb + 16908288);      //  8 MB
    char*  AHL =         (wsb + 27918336);      //  8 MB f16 hi/lo frag-major
    float* pdg = (float*)(wsb + 36306944);      //  5.24 MB partial dists
    int*   pig = (int*)  (wsb + 41549824);      //  5.24 MB partial ids

    k_transpose<<<512, 256, 0, stream>>>(x, Xt, sqn, AHL);
    k_ab<<<256, 256, 0, stream>>>(Xt, W, av, bvv);
    k_knn<<<4096, 64, 0, stream>>>(AHL, sqn, pdg, pig);
    k_out<<<512, 256, 0, stream>>>(av, bvv, pdg, pig, gamma, beta, rmean, rvar, out);
}

// Round 9
// 386.467 us; speedup vs baseline: 1.1987x; 1.1032x over previous
//
#include <hip/hip_runtime.h>

#define B 8
#define C 64
#define N 4096
#define O 64
#define KNN 20
#define PQ 8
#define BN_EPS 1e-5f
#define NEG_SLOPE 0.2f

typedef _Float16 f16x8 __attribute__((ext_vector_type(8)));
typedef float    f32x4 __attribute__((ext_vector_type(4)));
#define MFMA16(a, b, c) __builtin_amdgcn_mfma_f32_16x16x32_f16(a, b, c, 0, 0, 0)

// insert (r,m) into ascending-sorted top-KNN list, dropping old min d[0].
// precondition: r > d[0]. Tie-safe (insert below existing equal value).
// Branch-free parallel form: new_d[j] = med3(d[j], d[j+1], r); depth ~2.
__device__ __forceinline__ void sorted_insert(float (&d)[KNN], int (&id)[KNN],
                                              float r, int m) {
    bool c[KNN];
    #pragma unroll
    for (int j = 0; j < KNN; ++j) c[j] = d[j] < r;
    #pragma unroll
    for (int j = 0; j < KNN - 1; ++j) {
        d[j]  = __builtin_amdgcn_fmed3f(d[j], d[j + 1], r);
        id[j] = c[j + 1] ? id[j + 1] : (c[j] ? m : id[j]);
    }
    d[KNN - 1]  = c[KNN - 1] ? r : d[KNN - 1];
    id[KNN - 1] = c[KNN - 1] ? m : id[KNN - 1];
}

// -------- K0: x (B,C,N) -> Xt (B,N,C) fp32, sq = ||x_n||^2, and AHL: f16 hi/lo
// frag-major: per 16-row group (4096 B): [term][khalf][quad][slot16][8 f16]
__global__ __launch_bounds__(256) void k_transpose(const float* __restrict__ x,
                                                   float* __restrict__ Xt,
                                                   float* __restrict__ sq,
                                                   char* __restrict__ AHL) {
    __shared__ float lds[C][65];
    int b    = blockIdx.x >> 6;
    int n0   = (blockIdx.x & 63) << 6;
    int lane = threadIdx.x & 63;
    int w    = threadIdx.x >> 6;
    #pragma unroll
    for (int i = 0; i < 16; ++i) {
        int c = w * 16 + i;
        lds[c][lane] = x[(size_t)b * C * N + (size_t)c * N + n0 + lane];
    }
    __syncthreads();
    #pragma unroll
    for (int i = 0; i < 16; ++i) {
        int nl = w * 16 + i;
        Xt[(size_t)b * N * C + (size_t)(n0 + nl) * C + lane] = lds[lane][nl];
    }
    // sq via quad-partial reduce: thread t owns n=t>>2, c-range (t&3)*16..+16.
    {
        int n_loc = threadIdx.x >> 2;
        int cg    = threadIdx.x & 3;
        float s = 0.f;
        #pragma unroll
        for (int ii = 0; ii < 16; ++ii) {
            float v = lds[cg * 16 + ii][n_loc];
            s = fmaf(v, v, s);
        }
        s += __shfl_xor(s, 1, 64);
        s += __shfl_xor(s, 2, 64);
        if (cg == 0) sq[b * N + n0 + n_loc] = s;
    }
    int s2  = threadIdx.x & 15;
    int rem = threadIdx.x >> 4;
    int qd  = rem & 3;
    int hh  = (rem >> 2) & 1;
    int tt  = rem >> 3;
    int kb  = hh * 32 + qd * 8;
    for (int i = 0; i < 4; ++i) {
        int rowl = i * 16 + s2;
        f16x8 pk;
        #pragma unroll
        for (int ii = 0; ii < 8; ++ii) {
            float v = lds[kb + ii][rowl];
            _Float16 hv = (_Float16)v;
            if (tt) hv = (_Float16)(v - (float)hv);
            pk[ii] = hv;
        }
        char* dst = AHL + ((size_t)b << 20) + (size_t)((n0 >> 4) + i) * 4096
                  + tt * 2048 + hh * 1024 + qd * 256 + s2 * 16;
        *(f16x8*)dst = pk;
    }
}

// -------- K1: a = X*(W1-W2)^T, bvec = X*W2^T
// b = bid&7: XCD-pinned (bid%8 = XCD round-robin) -> Xt[b] (1 MB) L2-local.
__global__ __launch_bounds__(256, 2) void k_ab(const float* __restrict__ Xt,
                                               const float* __restrict__ W,
                                               float* __restrict__ av,
                                               float* __restrict__ bv) {
    int b  = blockIdx.x & 7;
    int n0 = ((blockIdx.x >> 3) & 31) << 7;
    int o  = threadIdx.x & 63;
    int w  = __builtin_amdgcn_readfirstlane((int)(threadIdx.x >> 6));
    float wa[C], wb[C];
    #pragma unroll
    for (int c = 0; c < C; ++c) {
        float w1 = W[o * 2 * C + c];
        float w2 = W[o * 2 * C + C + c];
        wa[c] = w1 - w2;
        wb[c] = w2;
    }
    const float* xb = Xt + (size_t)b * N * C;
    for (int i = 0; i < 32; ++i) {
        int n = n0 + w * 32 + i;
        const float4* xr4 = (const float4*)(xb + (size_t)n * C);
        float aa = 0.f, bb = 0.f;
        #pragma unroll
        for (int c4 = 0; c4 < C / 4; ++c4) {
            float4 xv = xr4[c4];
            aa = fmaf(xv.x, wa[c4 * 4 + 0], aa);
            bb = fmaf(xv.x, wb[c4 * 4 + 0], bb);
            aa = fmaf(xv.y, wa[c4 * 4 + 1], aa);
            bb = fmaf(xv.y, wb[c4 * 4 + 1], bb);
            aa = fmaf(xv.z, wa[c4 * 4 + 2], aa);
            bb = fmaf(xv.z, wb[c4 * 4 + 2], bb);
            aa = fmaf(xv.w, wa[c4 * 4 + 3], aa);
            bb = fmaf(xv.w, wb[c4 * 4 + 3], bb);
        }
        size_t oidx = ((size_t)b * N + n) * O + o;
        av[oidx] = aa;
        bv[oidx] = bb;
    }
}

// -------- K2: single-pass streaming MFMA kNN (R6 base: proven 252 us).
// 1-wave blocks, grid 4096, b = bid&7 (XCD-pinned), h = bit3, qg = bid>>4.
// Drain economics (R6/R8 validated): cost = drain_rate x drain_cost, and the
// trigger is an ORDER STATISTIC (fastest of 64 lanes). This version:
//  - PQ=8 pending slots per lane;
//  - drain only on OVERFLOW: trigger when a FULL lane gets another hit
//    (max lane count >= 9 since last drain), not when any lane reaches PQ.
//    Early p~0.125/lane/step -> drains every ~34 steps (vs 5.6), amortized
//    ~20 instr/step vs R6's ~61.
// Correctness: candidates are only dropped when sc <= thr (thr = quad-max of
// lane d[0] <= running query-20th, the established bound). Full+pass forces
// a wave drain first, so queues never overflow. Pending entries survive to
// the final flush. Tie semantics unchanged.
// Tripwire: WRITE_SIZE ~10240 KB; launch_bounds(64,2) keeps VGPR cap high.
__global__ __launch_bounds__(64, 2) void k_knn(const char* __restrict__ AHL,
                                               const float* __restrict__ sq,
                                               float* __restrict__ pdg,
                                               int* __restrict__ pig) {
    int bid  = blockIdx.x;
    int qg   = bid >> 4;
    int b    = bid & 7;
    int h    = (bid >> 3) & 1;
    int lane = threadIdx.x & 63;
    int quad = lane >> 4;
    const char*  AHLb = AHL + ((size_t)b << 20);
    const float* sqb  = sq + b * N;
    int cbase0 = h * (N / 2);
    const char* Asrc = AHLb + (size_t)cbase0 * 256;

    // B-frags: this wave's query group qg: hi/lo x khalf (16 VGPRs)
    const char* qb = AHLb + (size_t)qg * 4096 + lane * 16;
    f16x8 bh0 = *(const f16x8*)(qb);
    f16x8 bh1 = *(const f16x8*)(qb + 1024);
    f16x8 bl0 = *(const f16x8*)(qb + 2048);
    f16x8 bl1 = *(const f16x8*)(qb + 3072);

    float d[KNN]; int id[KNN];
    float pv[PQ]; int pi[PQ]; int pc = 0;
    #pragma unroll
    for (int j = 0; j < PQ; ++j) { pv[j] = 0.f; pi[j] = 0; }

    // prefetch iter 0
    const char* p0 = Asrc + lane * 16;
    f16x8 na0 = *(const f16x8*)(p0);
    f16x8 na1 = *(const f16x8*)(p0 + 1024);
    f16x8 na2 = *(const f16x8*)(p0 + 2048);
    f16x8 na3 = *(const f16x8*)(p0 + 3072);
    float4 nsq = *(const float4*)(sqb + cbase0 + quad * 4);

    // ---- warm-fill: iters 0..4 (20 cands per lane) fill all KNN slots
    #pragma unroll
    for (int it = 0; it < 5; ++it) {
        f16x8 a0 = na0, a1 = na1, a2 = na2, a3 = na3;
        float4 sqv = nsq;
        {
            const char* p = Asrc + (size_t)(it + 1) * 4096 + lane * 16;
            na0 = *(const f16x8*)(p);
            na1 = *(const f16x8*)(p + 1024);
            na2 = *(const f16x8*)(p + 2048);
            na3 = *(const f16x8*)(p + 3072);
            nsq = *(const float4*)(sqb + cbase0 + (it + 1) * 16 + quad * 4);
        }
        f32x4 acc = {0.f, 0.f, 0.f, 0.f};
        acc = MFMA16(a0, bh0, acc);
        acc = MFMA16(a1, bh1, acc);
        acc = MFMA16(a0, bl0, acc);
        acc = MFMA16(a1, bl1, acc);
        acc = MFMA16(a2, bh0, acc);
        acc = MFMA16(a3, bh1, acc);
        int c0 = cbase0 + it * 16 + quad * 4;
        #pragma unroll
        for (int r = 0; r < 4; ++r) {
            float sc = fmaf(2.f, acc[r],
                            -((r == 0) ? sqv.x : (r == 1) ? sqv.y
                                       : (r == 2) ? sqv.z : sqv.w));
            d[it * 4 + r]  = sc;          // compile-time slot index
            id[it * 4 + r] = c0 + r;
        }
    }
    // one-time in-register bubble sort, ascending (compile-time indices)
    #pragma unroll
    for (int i = 0; i < KNN - 1; ++i) {
        #pragma unroll
        for (int j = 0; j < KNN - 1 - i; ++j) {
            bool sw = d[j] > d[j + 1];
            float tv = d[j]; int ti = id[j];
            d[j]      = sw ? d[j + 1] : d[j];
            id[j]     = sw ? id[j + 1] : id[j];
            d[j + 1]  = sw ? tv : d[j + 1];
            id[j + 1] = sw ? ti : id[j + 1];
        }
    }
    // shared threshold across the 4 quad-lanes serving this query
    float thr = d[0];
    thr = fmaxf(thr, __shfl_xor(thr, 16, 64));
    thr = fmaxf(thr, __shfl_xor(thr, 32, 64));

    #pragma unroll 1
    for (int it = 5; it < 128; ++it) {         // 16 cands per iter
        f16x8 a0 = na0, a1 = na1, a2 = na2, a3 = na3;
        float4 sqv = nsq;
        if (it + 1 < 128) {                    // issue next-iter loads early
            const char* p = Asrc + (size_t)(it + 1) * 4096 + lane * 16;
            na0 = *(const f16x8*)(p);
            na1 = *(const f16x8*)(p + 1024);
            na2 = *(const f16x8*)(p + 2048);
            na3 = *(const f16x8*)(p + 3072);
            nsq = *(const float4*)(sqb + cbase0 + (it + 1) * 16 + quad * 4);
        }
        f32x4 acc = {0.f, 0.f, 0.f, 0.f};
        acc = MFMA16(a0, bh0, acc);
        acc = MFMA16(a1, bh1, acc);
        acc = MFMA16(a0, bl0, acc);
        acc = MFMA16(a1, bl1, acc);
        acc = MFMA16(a2, bh0, acc);
        acc = MFMA16(a3, bh1, acc);
        int c0 = cbase0 + it * 16 + quad * 4;  // lane's 4 cands (row=quad*4+r)
        #pragma unroll
        for (int r = 0; r < 4; ++r) {
            float sc = fmaf(2.f, acc[r],
                            -((r == 0) ? sqv.x : (r == 1) ? sqv.y
                                       : (r == 2) ? sqv.z : sqv.w));
            bool pass = sc > thr;
            if (__any(pass && (pc == PQ))) {   // overflow imminent -> drain all
                #pragma unroll
                for (int j = 0; j < PQ; ++j)
                    if (j < pc && pv[j] > d[0]) sorted_insert(d, id, pv[j], pi[j]);
                pc = 0;
                float t = d[0];                // refresh shared threshold
                t = fmaxf(t, __shfl_xor(t, 16, 64));
                t = fmaxf(t, __shfl_xor(t, 32, 64));
                thr = fmaxf(thr, t);
            }
            if (pass) {                        // append (pc < PQ guaranteed)
                #pragma unroll
                for (int j = 0; j < PQ; ++j) {
                    bool sel = (pc == j);
                    pv[j] = sel ? sc : pv[j];
                    pi[j] = sel ? (c0 + r) : pi[j];
                }
                ++pc;
            }
        }
    }
    #pragma unroll
    for (int j = 0; j < PQ; ++j)               // final flush
        if (j < pc && pv[j] > d[0]) sorted_insert(d, id, pv[j], pi[j]);

    // in-wave quad-merge tournament via shuffles: 2,3 -> 0,1 then 1 -> 0
    #pragma unroll 1
    for (int step = 0; step < 2; ++step) {
        int off = (step == 0) ? 32 : 16;
        bool active = (step == 0) ? (quad < 2) : (quad == 0);
        for (int j = KNN - 1; j >= 0; --j) {   // descending; early-exit
            float rv = __shfl(d[j], lane + off, 64);
            int   ri = __shfl(id[j], lane + off, 64);
            bool ins = active && (rv > d[0]);
            if (!__any(ins)) break;
            if (ins) sorted_insert(d, id, rv, ri);
        }
    }
    if (lane < 16) {
        size_t rr = (size_t)b * N + qg * 16 + lane;
        float* po = pdg + (rr * 2 + h) * KNN;
        int*   qo = pig + (rr * 2 + h) * KNN;
        #pragma unroll
        for (int j = 0; j < KNN; ++j) { po[j] = d[j]; qo[j] = id[j]; }
    }
}

// -------- K3: fused merge + gather + BN/leaky + transpose-store.
// Phase A (R8 lesson: STAGE first, never serial dependent global loads):
//  A1: all 256 threads stage the 40 half-list scores per query into LDS
//      (coalesced unrolled loads; lds[][] reused as scratch - it is dead
//      until phase B writes it).
//  A2: threads 0..63 merge from LDS; the 20 id-loads from pig are issued as
//      NON-dependent gathers (load result never feeds control flow).
// b = bid&7: XCD-pinned -> each XCD gathers only its own bv[b] (1 MB L2-res).
__global__ __launch_bounds__(256) void k_out(const float* __restrict__ av,
                                             const float* __restrict__ bv,
                                             const float* __restrict__ pdg,
                                             const int* __restrict__ pig,
                                             const float* __restrict__ gamma,
                                             const float* __restrict__ beta,
                                             const float* __restrict__ rmean,
                                             const float* __restrict__ rvar,
                                             float* __restrict__ out) {
    __shared__ float lds[64][65];
    __shared__ int   ids[64][21];
    int b    = blockIdx.x & 7;
    int n0   = (blockIdx.x >> 3) << 6;
    int t    = threadIdx.x;
    int lane = t & 63;
    int w    = __builtin_amdgcn_readfirstlane((int)(t >> 6));
    // ---- A1: stage 40 scores/query into lds scratch (4 threads x 10 each)
    {
        int q    = t >> 2;
        int part = t & 3;
        const float* pr = pdg + ((size_t)b * N + n0 + q) * (2 * KNN);
        #pragma unroll
        for (int k = 0; k < 10; ++k)
            lds[q][part * 10 + k] = pr[part * 10 + k];
    }
    __syncthreads();
    // ---- A2: per-query 2-way merge (scores from LDS, ids pipelined)
    if (t < 64) {
        const int* qr = pig + ((size_t)b * N + n0 + t) * (2 * KNN);
        int i = KNN - 1, j = KNN - 1;
        #pragma unroll 1
        for (int o = 0; o < KNN; ++o) {
            bool t0 = (j < 0) || (i >= 0 && lds[t][i] >= lds[t][KNN + j]);
            ids[t][o] = t0 ? qr[i] : qr[KNN + j];
            if (t0) --i; else --j;
        }
    }
    __syncthreads();
    // ---- phase B: gather + epilogue
    int o = lane;
    float scale = gamma[o] * rsqrtf(rvar[o] + BN_EPS);
    float bias  = fmaf(-rmean[o], scale, beta[o]);
    const float* bvb = bv + (size_t)b * N * O;
    for (int i = 0; i < 16; ++i) {
        int nl = w * 16 + i;
        int n  = n0 + nl;
        float mx = -3.4e38f, mn = 3.4e38f;
        #pragma unroll
        for (int j = 0; j < KNN; ++j) {
            float v = bvb[(size_t)ids[nl][j] * O + o];
            mx = fmaxf(mx, v);
            mn = fminf(mn, v);
        }
        float a   = av[((size_t)b * N + n) * O + o];
        float sel = (scale >= 0.f) ? (a + mx) : (a + mn);
        float y   = fmaf(sel, scale, bias);
        y = fmaxf(y, NEG_SLOPE * y);
        lds[o][nl] = y;
    }
    __syncthreads();
    int r  = threadIdx.x >> 2;
    int c0 = (threadIdx.x & 3) << 4;
    float* ob = out + (size_t)b * O * N + (size_t)r * N + n0;
    #pragma unroll
    for (int j = 0; j < 16; j += 4) {
        float4 v;
        v.x = lds[r][c0 + j + 0];
        v.y = lds[r][c0 + j + 1];
        v.z = lds[r][c0 + j + 2];
        v.w = lds[r][c0 + j + 3];
        *(float4*)(ob + c0 + j) = v;
    }
}

extern "C" void kernel_launch(void* const* d_in, const int* in_sizes, int n_in,
                              void* d_out, int out_size, void* d_ws, size_t ws_size,
                              hipStream_t stream) {
    const float* x     = (const float*)d_in[0];
    const float* W     = (const float*)d_in[1];
    const float* gamma = (const float*)d_in[2];
    const float* beta  = (const float*)d_in[3];
    const float* rmean = (const float*)d_in[4];
    const float* rvar  = (const float*)d_in[5];
    float* out = (float*)d_out;

    char* wsb = (char*)d_ws;
    float* Xt  = (float*)(wsb);                 //  8 MB
    float* sqn = (float*)(wsb + 8388608);       //  128 KB
    float* av  = (float*)(wsb + 8519680);       //  8 MB
    float* bvv = (float*)(wsb + 16908288);      //  8 MB
    char*  AHL =         (wsb + 27918336);      //  8 MB f16 hi/lo frag-major
    float* pdg = (float*)(wsb + 36306944);      //  5.24 MB partial dists
    int*   pig = (int*)  (wsb + 41549824);      //  5.24 MB partial ids

    k_transpose<<<512, 256, 0, stream>>>(x, Xt, sqn, AHL);
    k_ab<<<256, 256, 0, stream>>>(Xt, W, av, bvv);
    k_knn<<<4096, 64, 0, stream>>>(AHL, sqn, pdg, pig);
    k_out<<<512, 256, 0, stream>>>(av, bvv, pdg, pig, gamma, beta, rmean, rvar, out);
}